// Round 3
// baseline (639.885 us; speedup 1.0000x reference)
//
#include <hip/hip_runtime.h>
#include <stdint.h>

// MHATokenNoLayerNorm on MI355X (gfx950).
// fp32 -> (bf16 hi, bf16 lo) split; all GEMM-shaped ops use
// mfma_f32_16x16x32_bf16 with 3-term split product (hh + hl + lh).
// Pipeline:
//   splitT(Wq/Wkv/Wo)
//   gemm<0,AF32>: q = ini_q @ Wq            -> q hi/lo natural
//   gemm<3,AF32>: kv = ini_k @ Wkv          -> kvN [b,s,h][t][d] + kvT [b,s,h][d][t]
//   attn: per (b,h,s-octet) x 8 s-iters: S^T = K Q^T, lane-local softmax,
//         O = P kvT -> res hi/lo   (1 barrier/iter, dbuf K via global_load_lds)
//   gemm<1,gload>: out = res @ Wo + bo
// LDS conflicts: gload tiles use XOR involution (source-preswizzle + read),
// reg-staged A uses +8 padding (LDT=40).

typedef __bf16 bf16_t;
typedef __attribute__((ext_vector_type(8))) __bf16 bf16x8;
typedef __attribute__((ext_vector_type(4))) __bf16 bf16x4;
typedef __attribute__((ext_vector_type(4))) float f32x4;

#define HDIM 768

__device__ __forceinline__ void gload16(const bf16_t* g, bf16_t* l) {
  __builtin_amdgcn_global_load_lds(
      (const __attribute__((address_space(1))) void*)g,
      (__attribute__((address_space(3))) void*)l, 16, 0, 0);
}

// ---------------- weight split+transpose ----------------
__global__ __launch_bounds__(256) void splitT_kernel(const float* __restrict__ w,
                                                     bf16_t* __restrict__ hT,
                                                     bf16_t* __restrict__ lT) {
  int idx = blockIdx.x * 256 + threadIdx.x;
  int k = idx / HDIM, n = idx % HDIM;
  float v = w[idx];
  bf16_t hb = (bf16_t)v;
  hT[n * HDIM + k] = hb;
  lT[n * HDIM + k] = (bf16_t)(v - (float)hb);
}

// ---------------- split-bf16 GEMM ----------------
// C[M,768] = A[M,768] @ W[768,768]; W transposed+pre-split (WT[n][k] hi/lo).
// AF32: A staged from fp32 global, split in regs, padded LDS (LDT=40).
// else: A staged via global_load_lds, linear [128][32] + involution swizzle.
// B always global_load_lds + involution swizzle.
// EPI 0: natural bf16 hi/lo. EPI 1: f32 + bias. EPI 3: kvT AND kvN hi/lo.
template <int EPI, bool AF32>
__global__ __launch_bounds__(256) void gemm_kernel(
    const float* __restrict__ Agf,
    const bf16_t* __restrict__ Agh, const bf16_t* __restrict__ Agl,
    const bf16_t* __restrict__ Bgh, const bf16_t* __restrict__ Bgl,
    bf16_t* __restrict__ Ch, bf16_t* __restrict__ Cl,
    bf16_t* __restrict__ CTh, bf16_t* __restrict__ CTl,
    bf16_t* __restrict__ CNh, bf16_t* __restrict__ CNl,
    float* __restrict__ Cf, const float* __restrict__ bias) {
  const int LDA = AF32 ? 40 : 32;
  __shared__ bf16_t sAh[128 * 40], sAl[128 * 40];
  __shared__ bf16_t sBh[128 * 32], sBl[128 * 32];
  const int nwg = gridDim.x;
  const int cpx = nwg >> 3;
  const int g = blockIdx.x;
  const int wg = (g & 7) * cpx + (g >> 3);
  const int bn = wg % 6, bm = wg / 6;
  const int tid = threadIdx.x, lane = tid & 63, w = tid >> 6;
  const int wr = (w >> 1) * 64, wc = (w & 1) * 64;
  const int l15 = lane & 15, l4 = lane >> 4;
  f32x4 acc[4][4] = {};

  for (int kt = 0; kt < 24; ++kt) {
    const int k0 = kt * 32;
    __syncthreads();
    if constexpr (AF32) {
#pragma unroll
      for (int j = 0; j < 4; ++j) {
        const int c = tid + j * 256;
        const int row = c >> 3, cg = c & 7;
        const float4 v4 =
            *(const float4*)&Agf[(size_t)(bm * 128 + row) * HDIM + k0 + cg * 4];
        const float vv[4] = {v4.x, v4.y, v4.z, v4.w};
        bf16x4 hv, lv;
#pragma unroll
        for (int e = 0; e < 4; ++e) {
          bf16_t hb = (bf16_t)vv[e];
          hv[e] = hb;
          lv[e] = (bf16_t)(vv[e] - (float)hb);
        }
        *(bf16x4*)&sAh[row * 40 + cg * 4] = hv;
        *(bf16x4*)&sAl[row * 40 + cg * 4] = lv;
      }
    } else {
#pragma unroll
      for (int j = 0; j < 2; ++j) {
        const int c0 = j * 256 + w * 64;
        const int c = c0 + lane;
        const int row = c >> 2, slot = c & 3;
        const size_t ga = (size_t)(bm * 128 + row) * HDIM + k0 +
                          ((slot ^ ((row >> 1) & 3)) * 8);
        gload16(&Agh[ga], &sAh[c0 * 8]);
        gload16(&Agl[ga], &sAl[c0 * 8]);
      }
    }
#pragma unroll
    for (int j = 0; j < 2; ++j) {
      const int c0 = j * 256 + w * 64;
      const int c = c0 + lane;
      const int row = c >> 2, slot = c & 3;
      const size_t gb = (size_t)(bn * 128 + row) * HDIM + k0 +
                        ((slot ^ ((row >> 1) & 3)) * 8);
      gload16(&Bgh[gb], &sBh[c0 * 8]);
      gload16(&Bgl[gb], &sBl[c0 * 8]);
    }
    __syncthreads();
    bf16x8 a_h[4], a_l[4], b_h[4], b_l[4];
#pragma unroll
    for (int m = 0; m < 4; ++m) {
      const int rowa = wr + m * 16 + l15;
      const int ra = AF32 ? rowa * 40 + l4 * 8
                          : rowa * 32 + ((l4 ^ ((rowa >> 1) & 3)) * 8);
      a_h[m] = *(const bf16x8*)&sAh[ra];
      a_l[m] = *(const bf16x8*)&sAl[ra];
      const int rowb = wc + m * 16 + l15;
      const int rb = rowb * 32 + ((l4 ^ ((rowb >> 1) & 3)) * 8);
      b_h[m] = *(const bf16x8*)&sBh[rb];
      b_l[m] = *(const bf16x8*)&sBl[rb];
    }
#pragma unroll
    for (int m = 0; m < 4; ++m)
#pragma unroll
      for (int n = 0; n < 4; ++n) {
        acc[m][n] = __builtin_amdgcn_mfma_f32_16x16x32_bf16(a_h[m], b_h[n], acc[m][n], 0, 0, 0);
        acc[m][n] = __builtin_amdgcn_mfma_f32_16x16x32_bf16(a_h[m], b_l[n], acc[m][n], 0, 0, 0);
        acc[m][n] = __builtin_amdgcn_mfma_f32_16x16x32_bf16(a_l[m], b_h[n], acc[m][n], 0, 0, 0);
      }
  }
  // epilogue: C/D frag layout col = lane&15, row = (lane>>4)*4 + j
#pragma unroll
  for (int m = 0; m < 4; ++m)
#pragma unroll
    for (int n = 0; n < 4; ++n) {
      const int row0 = bm * 128 + wr + m * 16 + l4 * 4;
      const int col = bn * 128 + wc + n * 16 + l15;
      if constexpr (EPI == 1) {
        const float bv = bias[col];
#pragma unroll
        for (int j = 0; j < 4; ++j)
          Cf[(size_t)(row0 + j) * HDIM + col] = acc[m][n][j] + bv;
      } else if constexpr (EPI == 0) {
#pragma unroll
        for (int j = 0; j < 4; ++j) {
          const float v = acc[m][n][j];
          const bf16_t hb = (bf16_t)v;
          Ch[(size_t)(row0 + j) * HDIM + col] = hb;
          Cl[(size_t)(row0 + j) * HDIM + col] = (bf16_t)(v - (float)hb);
        }
      } else {  // EPI == 3: kvT [b,s,h][d][t] (b64) + kvN [b,s,h][t][d] (scalar)
        bf16x4 hv, lv;
#pragma unroll
        for (int j = 0; j < 4; ++j) {
          const float v = acc[m][n][j];
          const bf16_t hb = (bf16_t)v;
          hv[j] = hb;
          lv[j] = (bf16_t)(v - (float)hb);
        }
        const int b = row0 >> 12, s = (row0 >> 6) & 63, t0 = row0 & 63;
        const int hh = col >> 6, d = col & 63;
        const size_t base = ((size_t)((b * 64 + s) * 12 + hh)) * 4096;
        *(bf16x4*)&CTh[base + d * 64 + t0] = hv;
        *(bf16x4*)&CTl[base + d * 64 + t0] = lv;
#pragma unroll
        for (int j = 0; j < 4; ++j) {
          CNh[base + (t0 + j) * 64 + d] = hv[j];
          CNl[base + (t0 + j) * 64 + d] = lv[j];
        }
      }
    }
}

// ---------------- fused attention ----------------
// Block = (s-octet, h, b): 768 blocks, 4 waves, 8 s-iterations.
// Per iter: stage K(next) via gload16 (swizzled source), QK^T swapped
// (S^T[t][q], A=K LDS, B=Q regs), lane-local softmax over t, P->LDS
// (wave-private rows), PV O[q][d] = mfma(A=P, B=kvT global), direct res
// stores. ONE __syncthreads per iter (drains staging).
__device__ __forceinline__ void stage_k(const bf16_t* __restrict__ gh,
                                        const bf16_t* __restrict__ gl,
                                        bf16_t* lh, bf16_t* ll,
                                        int w, int lane) {
#pragma unroll
  for (int j = 0; j < 2; ++j) {
    const int c0 = j * 256 + w * 64;
    const int c = c0 + lane;
    const int t = c >> 3, sl = c & 7;
    const int srcd = (sl ^ (t & 7)) * 8;
    gload16(&gh[t * 64 + srcd], &lh[c0 * 8]);
    gload16(&gl[t * 64 + srcd], &ll[c0 * 8]);
  }
}

__global__ __launch_bounds__(256, 3) void attn_kernel(
    const bf16_t* __restrict__ qh, const bf16_t* __restrict__ ql,
    const bf16_t* __restrict__ kvNh, const bf16_t* __restrict__ kvNl,
    const bf16_t* __restrict__ kvTh, const bf16_t* __restrict__ kvTl,
    const float* __restrict__ mask,
    bf16_t* __restrict__ resh, bf16_t* __restrict__ resl) {
  const int sq = blockIdx.x, hh = blockIdx.y, b = blockIdx.z;
  const int s0 = sq * 8;
  const int tid = threadIdx.x, lane = tid & 63, w = tid >> 6;
  const int l15 = lane & 15, l4 = lane >> 4;
  __shared__ bf16_t Ksm[2][2][64 * 64];  // [buf][hi/lo][t*64 + swz slot]
  __shared__ bf16_t Ph[64 * 72], Pl[64 * 72];
  __shared__ float mk[8 * 64];

  {  // mask for the 8 s rows, pre-scaled
    const int i2 = tid * 2;
    const float2 mv = *(const float2*)
        &mask[((size_t)(b * 64 + s0 + (i2 >> 6))) * 64 + (i2 & 63)];
    mk[i2] = mv.x * -10000.0f;
    mk[i2 + 1] = mv.y * -10000.0f;
  }

  // Q fragments (B-operand: col q = w*16 + l15), hoisted for all 8 iters
  const size_t qbase = ((size_t)(b * 64 + w * 16 + l15)) * HDIM + hh * 64;
  bf16x8 qf_h[2], qf_l[2];
#pragma unroll
  for (int ks = 0; ks < 2; ++ks) {
    qf_h[ks] = *(const bf16x8*)&qh[qbase + ks * 32 + l4 * 8];
    qf_l[ks] = *(const bf16x8*)&ql[qbase + ks * 32 + l4 * 8];
  }

  const size_t hb0 = ((size_t)((b * 64 + s0) * 12 + hh)) * 4096;  // s-stride 12*4096
  const size_t SSTR = 12 * 4096;

  stage_k(&kvNh[hb0], &kvNl[hb0], &Ksm[0][0][0], &Ksm[0][1][0], w, lane);
  __syncthreads();

  const int q = w * 16 + l15;
  for (int si = 0; si < 8; ++si) {
    const int cur = si & 1;
    const int sn = (si < 7) ? si + 1 : 7;
    stage_k(&kvNh[hb0 + sn * SSTR], &kvNl[hb0 + sn * SSTR],
            &Ksm[cur ^ 1][0][0], &Ksm[cur ^ 1][1][0], w, lane);

    // ---- S^T[t][q] = K . Q^T ----
    f32x4 St[4] = {};
#pragma unroll
    for (int ks = 0; ks < 2; ++ks) {
#pragma unroll
      for (int mf = 0; mf < 4; ++mf) {
        const int t = mf * 16 + l15;
        const int off = t * 64 + (((ks * 4 + l4) ^ (t & 7)) * 8);
        const bf16x8 kh8 = *(const bf16x8*)&Ksm[cur][0][off];
        const bf16x8 kl8 = *(const bf16x8*)&Ksm[cur][1][off];
        St[mf] = __builtin_amdgcn_mfma_f32_16x16x32_bf16(kh8, qf_h[ks], St[mf], 0, 0, 0);
        St[mf] = __builtin_amdgcn_mfma_f32_16x16x32_bf16(kh8, qf_l[ks], St[mf], 0, 0, 0);
        St[mf] = __builtin_amdgcn_mfma_f32_16x16x32_bf16(kl8, qf_h[ks], St[mf], 0, 0, 0);
      }
    }

    // ---- softmax over t (lane-local 16 vals: t = mf*16 + l4*4 + j) ----
    float p[16];
    float mx = -1e30f;
#pragma unroll
    for (int mf = 0; mf < 4; ++mf)
#pragma unroll
      for (int j = 0; j < 4; ++j) {
        const float v = St[mf][j] * 0.125f + mk[si * 64 + mf * 16 + l4 * 4 + j];
        p[mf * 4 + j] = v;
        mx = fmaxf(mx, v);
      }
    mx = fmaxf(mx, __shfl_xor(mx, 16));
    mx = fmaxf(mx, __shfl_xor(mx, 32));
    float sum = 0.f;
#pragma unroll
    for (int i = 0; i < 16; ++i) {
      const float e = __expf(p[i] - mx);
      p[i] = e;
      sum += e;
    }
    sum += __shfl_xor(sum, 16);
    sum += __shfl_xor(sum, 32);
    const float inv = 1.0f / sum;

    // ---- P[q][t] hi/lo (wave-private rows; intra-wave reuse, no barrier) ----
#pragma unroll
    for (int mf = 0; mf < 4; ++mf) {
      bf16x4 hv, lv;
#pragma unroll
      for (int j = 0; j < 4; ++j) {
        const float v = p[mf * 4 + j] * inv;
        const bf16_t hb = (bf16_t)v;
        hv[j] = hb;
        lv[j] = (bf16_t)(v - (float)hb);
      }
      *(bf16x4*)&Ph[q * 72 + mf * 16 + l4 * 4] = hv;
      *(bf16x4*)&Pl[q * 72 + mf * 16 + l4 * 4] = lv;
    }

    // ---- O[q][d] = P @ kvT^T rows (B = kvT[d][t] global-direct) ----
    f32x4 O[4] = {};
    const size_t tb = hb0 + si * SSTR;
#pragma unroll
    for (int ks = 0; ks < 2; ++ks) {
      const bf16x8 pa = *(const bf16x8*)&Ph[q * 72 + ks * 32 + l4 * 8];
      const bf16x8 pb = *(const bf16x8*)&Pl[q * 72 + ks * 32 + l4 * 8];
#pragma unroll
      for (int nf = 0; nf < 4; ++nf) {
        const size_t bb = tb + (size_t)(nf * 16 + l15) * 64 + ks * 32 + l4 * 8;
        const bf16x8 vh = *(const bf16x8*)&kvTh[bb];
        const bf16x8 vl = *(const bf16x8*)&kvTl[bb];
        O[nf] = __builtin_amdgcn_mfma_f32_16x16x32_bf16(pa, vh, O[nf], 0, 0, 0);
        O[nf] = __builtin_amdgcn_mfma_f32_16x16x32_bf16(pa, vl, O[nf], 0, 0, 0);
        O[nf] = __builtin_amdgcn_mfma_f32_16x16x32_bf16(pb, vh, O[nf], 0, 0, 0);
      }
    }
    __syncthreads();  // staged K(next) ready; P safe to rewrite next iter

    // ---- res[b,q,s][hh*64+d]: row qo = w*16 + l4*4 + j, col d = nf*16+l15
#pragma unroll
    for (int nf = 0; nf < 4; ++nf)
#pragma unroll
      for (int j = 0; j < 4; ++j) {
        const int qo = w * 16 + l4 * 4 + j;
        const size_t idx =
            ((size_t)((b * 64 + qo) * 64 + s0 + si)) * HDIM + hh * 64 + nf * 16 + l15;
        const float v = O[nf][j];
        const bf16_t hb = (bf16_t)v;
        resh[idx] = hb;
        resl[idx] = (bf16_t)(v - (float)hb);
      }
  }
}

// ---------------- launch ----------------
extern "C" void kernel_launch(void* const* d_in, const int* in_sizes, int n_in,
                              void* d_out, int out_size, void* d_ws, size_t ws_size,
                              hipStream_t stream) {
  const float* ini_q = (const float*)d_in[0];
  const float* ini_k = (const float*)d_in[1];
  const float* mask = (const float*)d_in[2];
  const float* Wq = (const float*)d_in[3];
  const float* Wkv = (const float*)d_in[4];
  const float* Wo = (const float*)d_in[5];
  const float* bo = (const float*)d_in[6];
  float* out = (float*)d_out;

  const size_t SQ = 512ull * HDIM;
  const size_t SK = 32768ull * HDIM;
  const size_t SW = 768ull * HDIM;

  char* p = (char*)d_ws;
  auto carve = [&](size_t bytes) {
    char* r = p;
    p += (bytes + 255) & ~(size_t)255;
    return r;
  };
  bf16_t* wq_h = (bf16_t*)carve(SW * 2);
  bf16_t* wq_l = (bf16_t*)carve(SW * 2);
  bf16_t* wkv_h = (bf16_t*)carve(SW * 2);
  bf16_t* wkv_l = (bf16_t*)carve(SW * 2);
  bf16_t* wo_h = (bf16_t*)carve(SW * 2);
  bf16_t* wo_l = (bf16_t*)carve(SW * 2);
  bf16_t* q_h = (bf16_t*)carve(SQ * 2);
  bf16_t* q_l = (bf16_t*)carve(SQ * 2);
  bf16_t* kvT_h = (bf16_t*)carve(SK * 2);
  bf16_t* kvT_l = (bf16_t*)carve(SK * 2);
  bf16_t* kvN_h = (bf16_t*)carve(SK * 2);
  bf16_t* kvN_l = (bf16_t*)carve(SK * 2);
  bf16_t* res_h = (bf16_t*)carve(SK * 2);
  bf16_t* res_l = (bf16_t*)carve(SK * 2);
  if ((size_t)(p - (char*)d_ws) > ws_size) return;  // ws too small: fail visibly

  splitT_kernel<<<dim3(SW / 256), 256, 0, stream>>>(Wq, wq_h, wq_l);
  splitT_kernel<<<dim3(SW / 256), 256, 0, stream>>>(Wkv, wkv_h, wkv_l);
  splitT_kernel<<<dim3(SW / 256), 256, 0, stream>>>(Wo, wo_h, wo_l);

  // q = ini_q @ Wq
  gemm_kernel<0, true><<<dim3(24), 256, 0, stream>>>(
      ini_q, nullptr, nullptr, wq_h, wq_l, q_h, q_l, nullptr, nullptr,
      nullptr, nullptr, nullptr, nullptr);
  // kv = ini_k @ Wkv -> kvT + kvN
  gemm_kernel<3, true><<<dim3(1536), 256, 0, stream>>>(
      ini_k, nullptr, nullptr, wkv_h, wkv_l, nullptr, nullptr, kvT_h, kvT_l,
      kvN_h, kvN_l, nullptr, nullptr);
  // attention
  attn_kernel<<<dim3(8, 12, 8), 256, 0, stream>>>(
      q_h, q_l, kvN_h, kvN_l, kvT_h, kvT_l, mask, res_h, res_l);
  // out = res @ Wo + bo
  gemm_kernel<1, false><<<dim3(1536), 256, 0, stream>>>(
      nullptr, res_h, res_l, wo_h, wo_l, nullptr, nullptr, nullptr, nullptr,
      nullptr, nullptr, out, bo);
}

// Round 4
// 506.513 us; speedup vs baseline: 1.2633x; 1.2633x over previous
//
#include <hip/hip_runtime.h>
#include <stdint.h>

// MHATokenNoLayerNorm on MI355X (gfx950).
// fp32 -> (bf16 hi, bf16 lo) split; all GEMM-shaped ops use
// mfma_f32_16x16x32_bf16 with 3-term split product (hh + hl + lh).
// Pipeline:
//   splitT3: Wq/Wkv/Wo -> transposed hi/lo (LDS-tiled transpose)
//   gemm<0,AF32>: q = ini_q @ Wq           -> q hi/lo natural
//   gemm<2,AF32>: kv = ini_k @ Wkv         -> kvN [b,s,h][t][d] hi/lo ONLY
//   attn: per (b,h,s-octet) x 8 s-iters: reg-staged K (single LDS buf,
//         XOR-swizzled), S^T = K Q^T, lane-local softmax, VT built in LDS,
//         O = P VT -> res hi/lo. 2 barriers/iter.
//   gemm<1,gload>: out = res @ Wo + bo
// All LDS access patterns bank-checked: staging writes/fragment reads free;
// AF32 A-writes now use the same 16B-slot involution as gload (r3 had ~256
// conflict-cycles/kt from the padded-40 b64 writes).

typedef __bf16 bf16_t;
typedef __attribute__((ext_vector_type(8))) __bf16 bf16x8;
typedef __attribute__((ext_vector_type(4))) __bf16 bf16x4;
typedef __attribute__((ext_vector_type(4))) float f32x4;

#define HDIM 768

__device__ __forceinline__ void gload16(const bf16_t* g, bf16_t* l) {
  __builtin_amdgcn_global_load_lds(
      (const __attribute__((address_space(1))) void*)g,
      (__attribute__((address_space(3))) void*)l, 16, 0, 0);
}

// ---------------- weight split+transpose (LDS-tiled, coalesced) ----------------
__global__ __launch_bounds__(256) void splitT3_kernel(
    const float* __restrict__ W0, const float* __restrict__ W1,
    const float* __restrict__ W2,
    bf16_t* __restrict__ h0, bf16_t* __restrict__ l0,
    bf16_t* __restrict__ h1, bf16_t* __restrict__ l1,
    bf16_t* __restrict__ h2, bf16_t* __restrict__ l2) {
  const int kt = blockIdx.x * 64, nt = blockIdx.y * 64, ws = blockIdx.z;
  const float* W = ws == 0 ? W0 : (ws == 1 ? W1 : W2);
  bf16_t* H = ws == 0 ? h0 : (ws == 1 ? h1 : h2);
  bf16_t* L = ws == 0 ? l0 : (ws == 1 ? l1 : l2);
  __shared__ bf16_t Th[64 * 72], Tl[64 * 72];
  const int tid = threadIdx.x;
  const int r0 = tid >> 4, c0 = (tid & 15) * 4;
#pragma unroll
  for (int rg = 0; rg < 4; ++rg) {
    const int r = r0 + rg * 16;
    const float4 v = *(const float4*)&W[(size_t)(kt + r) * HDIM + nt + c0];
    const float vv[4] = {v.x, v.y, v.z, v.w};
#pragma unroll
    for (int e = 0; e < 4; ++e) {
      const bf16_t hb = (bf16_t)vv[e];
      Th[(c0 + e) * 72 + r] = hb;
      Tl[(c0 + e) * 72 + r] = (bf16_t)(vv[e] - (float)hb);
    }
  }
  __syncthreads();
  const int n = tid >> 2, kc = (tid & 3) * 16;
  bf16x8 oh[2], ol[2];
#pragma unroll
  for (int e = 0; e < 16; ++e) {
    oh[e >> 3][e & 7] = Th[n * 72 + kc + e];
    ol[e >> 3][e & 7] = Tl[n * 72 + kc + e];
  }
  const size_t ob = (size_t)(nt + n) * HDIM + kt + kc;
  *(bf16x8*)&H[ob] = oh[0];
  *(bf16x8*)&H[ob + 8] = oh[1];
  *(bf16x8*)&L[ob] = ol[0];
  *(bf16x8*)&L[ob + 8] = ol[1];
}

// ---------------- split-bf16 GEMM ----------------
// C[M,768] = A[M,768] @ W[768,768]; W transposed+pre-split (WT[n][k] hi/lo).
// LDS: linear [128][32] bf16 rows (64B), 16B slots XOR-involuted by
// ((row>>1)&3) on BOTH write/source and read sides.
// EPI 0: natural bf16 hi/lo. EPI 1: f32 + bias. EPI 2: kvN [b,s,h][t][d].
template <int EPI, bool AF32>
__global__ __launch_bounds__(256) void gemm_kernel(
    const float* __restrict__ Agf,
    const bf16_t* __restrict__ Agh, const bf16_t* __restrict__ Agl,
    const bf16_t* __restrict__ Bgh, const bf16_t* __restrict__ Bgl,
    bf16_t* __restrict__ Ch, bf16_t* __restrict__ Cl,
    bf16_t* __restrict__ CNh, bf16_t* __restrict__ CNl,
    float* __restrict__ Cf, const float* __restrict__ bias) {
  __shared__ bf16_t sAh[128 * 32], sAl[128 * 32];
  __shared__ bf16_t sBh[128 * 32], sBl[128 * 32];
  const int nwg = gridDim.x;
  const int cpx = nwg >> 3;
  const int g = blockIdx.x;
  const int wg = (g & 7) * cpx + (g >> 3);
  const int bn = wg % 6, bm = wg / 6;
  const int tid = threadIdx.x, lane = tid & 63, w = tid >> 6;
  const int wr = (w >> 1) * 64, wc = (w & 1) * 64;
  const int l15 = lane & 15, l4 = lane >> 4;
  f32x4 acc[4][4] = {};

  for (int kt = 0; kt < 24; ++kt) {
    const int k0 = kt * 32;
    __syncthreads();
    if constexpr (AF32) {
      // A tile 128x32 f32; split in regs; b64 writes at involuted 16B slots.
#pragma unroll
      for (int j = 0; j < 4; ++j) {
        const int c = tid + j * 256;
        const int row = c >> 3, cg = c & 7;
        const float4 v4 =
            *(const float4*)&Agf[(size_t)(bm * 128 + row) * HDIM + k0 + cg * 4];
        const float vv[4] = {v4.x, v4.y, v4.z, v4.w};
        bf16x4 hv, lv;
#pragma unroll
        for (int e = 0; e < 4; ++e) {
          const bf16_t hb = (bf16_t)vv[e];
          hv[e] = hb;
          lv[e] = (bf16_t)(vv[e] - (float)hb);
        }
        const int off =
            row * 32 + (((cg >> 1) ^ ((row >> 1) & 3)) * 8) + (cg & 1) * 4;
        *(bf16x4*)&sAh[off] = hv;
        *(bf16x4*)&sAl[off] = lv;
      }
    } else {
#pragma unroll
      for (int j = 0; j < 2; ++j) {
        const int c0 = j * 256 + w * 64;
        const int c = c0 + lane;
        const int row = c >> 2, slot = c & 3;
        const size_t ga = (size_t)(bm * 128 + row) * HDIM + k0 +
                          ((slot ^ ((row >> 1) & 3)) * 8);
        gload16(&Agh[ga], &sAh[c0 * 8]);
        gload16(&Agl[ga], &sAl[c0 * 8]);
      }
    }
#pragma unroll
    for (int j = 0; j < 2; ++j) {
      const int c0 = j * 256 + w * 64;
      const int c = c0 + lane;
      const int row = c >> 2, slot = c & 3;
      const size_t gb = (size_t)(bn * 128 + row) * HDIM + k0 +
                        ((slot ^ ((row >> 1) & 3)) * 8);
      gload16(&Bgh[gb], &sBh[c0 * 8]);
      gload16(&Bgl[gb], &sBl[c0 * 8]);
    }
    __syncthreads();
    bf16x8 a_h[4], a_l[4], b_h[4], b_l[4];
#pragma unroll
    for (int m = 0; m < 4; ++m) {
      const int rowa = wr + m * 16 + l15;
      const int ra = rowa * 32 + ((l4 ^ ((rowa >> 1) & 3)) * 8);
      a_h[m] = *(const bf16x8*)&sAh[ra];
      a_l[m] = *(const bf16x8*)&sAl[ra];
      const int rowb = wc + m * 16 + l15;
      const int rb = rowb * 32 + ((l4 ^ ((rowb >> 1) & 3)) * 8);
      b_h[m] = *(const bf16x8*)&sBh[rb];
      b_l[m] = *(const bf16x8*)&sBl[rb];
    }
#pragma unroll
    for (int m = 0; m < 4; ++m)
#pragma unroll
      for (int n = 0; n < 4; ++n) {
        acc[m][n] = __builtin_amdgcn_mfma_f32_16x16x32_bf16(a_h[m], b_h[n], acc[m][n], 0, 0, 0);
        acc[m][n] = __builtin_amdgcn_mfma_f32_16x16x32_bf16(a_h[m], b_l[n], acc[m][n], 0, 0, 0);
        acc[m][n] = __builtin_amdgcn_mfma_f32_16x16x32_bf16(a_l[m], b_h[n], acc[m][n], 0, 0, 0);
      }
  }
  // epilogue: C/D frag layout col = lane&15, row = (lane>>4)*4 + j
#pragma unroll
  for (int m = 0; m < 4; ++m)
#pragma unroll
    for (int n = 0; n < 4; ++n) {
      const int row0 = bm * 128 + wr + m * 16 + l4 * 4;
      const int col = bn * 128 + wc + n * 16 + l15;
      if constexpr (EPI == 1) {
        const float bv = bias[col];
#pragma unroll
        for (int j = 0; j < 4; ++j)
          Cf[(size_t)(row0 + j) * HDIM + col] = acc[m][n][j] + bv;
      } else if constexpr (EPI == 0) {
#pragma unroll
        for (int j = 0; j < 4; ++j) {
          const float v = acc[m][n][j];
          const bf16_t hb = (bf16_t)v;
          Ch[(size_t)(row0 + j) * HDIM + col] = hb;
          Cl[(size_t)(row0 + j) * HDIM + col] = (bf16_t)(v - (float)hb);
        }
      } else {  // EPI == 2: kvN [b,s,h][t][d]; lanes contiguous in d
        const int b = row0 >> 12, s = (row0 >> 6) & 63, t0 = row0 & 63;
        const int hh = col >> 6, d = col & 63;
        const size_t base = ((size_t)((b * 64 + s) * 12 + hh)) * 4096;
#pragma unroll
        for (int j = 0; j < 4; ++j) {
          const float v = acc[m][n][j];
          const bf16_t hb = (bf16_t)v;
          CNh[base + (t0 + j) * 64 + d] = hb;
          CNl[base + (t0 + j) * 64 + d] = (bf16_t)(v - (float)hb);
        }
      }
    }
}

// ---------------- fused attention ----------------
// Block = (s-octet, h, b): 768 blocks, 4 waves, 8 s-iterations.
// Reg-staged K (issue-early/write-late), single LDS K buffer with 16B-slot
// XOR swizzle. Per iter: QK^T (S^T[t][q]), VT[d][t] build, lane-local
// softmax, P write (wave-private), barrier, K overwrite, PV (A=P, B=VT),
// res stores, barrier.
__global__ __launch_bounds__(256, 3) void attn_kernel(
    const bf16_t* __restrict__ qh, const bf16_t* __restrict__ ql,
    const bf16_t* __restrict__ kvNh, const bf16_t* __restrict__ kvNl,
    const float* __restrict__ mask,
    bf16_t* __restrict__ resh, bf16_t* __restrict__ resl) {
  const int sq = blockIdx.x, hh = blockIdx.y, b = blockIdx.z;
  const int s0 = sq * 8;
  const int tid = threadIdx.x, lane = tid & 63, w = tid >> 6;
  const int l15 = lane & 15, l4 = lane >> 4;
  __shared__ bf16_t Kh[64 * 64], Kl[64 * 64];    // [t][swizzled 16B slots]
  __shared__ bf16_t VTh[64 * 72], VTl[64 * 72];  // [d][t], pad 72
  __shared__ bf16_t Ph[64 * 68], Pl[64 * 68];    // [q][t], pad 68
  __shared__ float mk[8 * 64];

  {  // mask for the 8 s rows, pre-scaled
    const int i2 = tid * 2;
    const float2 mv = *(const float2*)
        &mask[((size_t)(b * 64 + s0 + (i2 >> 6))) * 64 + (i2 & 63)];
    mk[i2] = mv.x * -10000.0f;
    mk[i2 + 1] = mv.y * -10000.0f;
  }

  // Q fragments (B-operand rows q = w*16 + l15), hoisted for all 8 iters
  const size_t qbase = ((size_t)(b * 64 + w * 16 + l15)) * HDIM + hh * 64;
  bf16x8 qf_h[2], qf_l[2];
#pragma unroll
  for (int ks = 0; ks < 2; ++ks) {
    qf_h[ks] = *(const bf16x8*)&qh[qbase + ks * 32 + l4 * 8];
    qf_l[ks] = *(const bf16x8*)&ql[qbase + ks * 32 + l4 * 8];
  }

  const size_t hb0 = ((size_t)((b * 64 + s0) * 12 + hh)) * 4096;
  const size_t SSTR = 12 * 4096;

  bf16x8 nxh[2], nxl[2];
  auto load_next = [&](int sn) {
#pragma unroll
    for (int j = 0; j < 2; ++j) {
      const int c = j * 256 + tid;
      const size_t src = hb0 + (size_t)sn * SSTR + (c >> 3) * 64 + (c & 7) * 8;
      nxh[j] = *(const bf16x8*)&kvNh[src];
      nxl[j] = *(const bf16x8*)&kvNl[src];
    }
  };
  auto write_K = [&]() {
#pragma unroll
    for (int j = 0; j < 2; ++j) {
      const int c = j * 256 + tid;
      const int t = c >> 3, sl = c & 7;
      const int off = t * 64 + ((sl ^ (t & 7)) * 8);
      *(bf16x8*)&Kh[off] = nxh[j];
      *(bf16x8*)&Kl[off] = nxl[j];
    }
  };

  load_next(0);
  write_K();
  __syncthreads();

  const int q = w * 16 + l15;
  for (int si = 0; si < 8; ++si) {
    if (si < 7) load_next(si + 1);  // HBM latency hides under QK^T+softmax

    // ---- S^T[t][q] = K . Q^T ----
    f32x4 St[4] = {};
#pragma unroll
    for (int ks = 0; ks < 2; ++ks) {
#pragma unroll
      for (int mf = 0; mf < 4; ++mf) {
        const int t = mf * 16 + l15;
        const int off = t * 64 + (((ks * 4 + l4) ^ (t & 7)) * 8);
        const bf16x8 kh8 = *(const bf16x8*)&Kh[off];
        const bf16x8 kl8 = *(const bf16x8*)&Kl[off];
        St[mf] = __builtin_amdgcn_mfma_f32_16x16x32_bf16(kh8, qf_h[ks], St[mf], 0, 0, 0);
        St[mf] = __builtin_amdgcn_mfma_f32_16x16x32_bf16(kh8, qf_l[ks], St[mf], 0, 0, 0);
        St[mf] = __builtin_amdgcn_mfma_f32_16x16x32_bf16(kl8, qf_h[ks], St[mf], 0, 0, 0);
      }
    }

    // ---- VT[d][t] build (thread: t = lane, d-range w*16..+16) ----
    {
      const int t = lane, sw = t & 7;
#pragma unroll
      for (int ri = 0; ri < 2; ++ri) {
        const int phys = (w * 2 + ri) ^ sw;
        const bf16x8 vh = *(const bf16x8*)&Kh[t * 64 + phys * 8];
        const bf16x8 vl = *(const bf16x8*)&Kl[t * 64 + phys * 8];
        const int d0 = w * 16 + ri * 8;
#pragma unroll
        for (int e = 0; e < 8; ++e) {
          VTh[(d0 + e) * 72 + t] = vh[e];
          VTl[(d0 + e) * 72 + t] = vl[e];
        }
      }
    }

    // ---- softmax over t (lane-local 16 vals: t = mf*16 + l4*4 + j) ----
    float p[16];
    float mx = -1e30f;
#pragma unroll
    for (int mf = 0; mf < 4; ++mf)
#pragma unroll
      for (int j = 0; j < 4; ++j) {
        const float v = St[mf][j] * 0.125f + mk[si * 64 + mf * 16 + l4 * 4 + j];
        p[mf * 4 + j] = v;
        mx = fmaxf(mx, v);
      }
    mx = fmaxf(mx, __shfl_xor(mx, 16));
    mx = fmaxf(mx, __shfl_xor(mx, 32));
    float sum = 0.f;
#pragma unroll
    for (int i = 0; i < 16; ++i) {
      const float e = __expf(p[i] - mx);
      p[i] = e;
      sum += e;
    }
    sum += __shfl_xor(sum, 16);
    sum += __shfl_xor(sum, 32);
    const float inv = 1.0f / sum;

    // ---- P[q][t] hi/lo (wave-private rows) ----
#pragma unroll
    for (int mf = 0; mf < 4; ++mf) {
      bf16x4 hv, lv;
#pragma unroll
      for (int j = 0; j < 4; ++j) {
        const float v = p[mf * 4 + j] * inv;
        const bf16_t hb = (bf16_t)v;
        hv[j] = hb;
        lv[j] = (bf16_t)(v - (float)hb);
      }
      *(bf16x4*)&Ph[q * 68 + mf * 16 + l4 * 4] = hv;
      *(bf16x4*)&Pl[q * 68 + mf * 16 + l4 * 4] = lv;
    }
    __syncthreads();  // all K reads done; VT complete

    if (si < 7) write_K();  // overwrite K with next tile (PV doesn't read K)

    // ---- O[q][d] = P @ V  (A = P rows q, B = VT rows d, k = t) ----
    f32x4 O[4] = {};
#pragma unroll
    for (int ks = 0; ks < 2; ++ks) {
      const bf16x8 pa = *(const bf16x8*)&Ph[q * 68 + ks * 32 + l4 * 8];
      const bf16x8 pb = *(const bf16x8*)&Pl[q * 68 + ks * 32 + l4 * 8];
#pragma unroll
      for (int nf = 0; nf < 4; ++nf) {
        const int d = nf * 16 + l15;
        const bf16x8 vh = *(const bf16x8*)&VTh[d * 72 + ks * 32 + l4 * 8];
        const bf16x8 vl = *(const bf16x8*)&VTl[d * 72 + ks * 32 + l4 * 8];
        O[nf] = __builtin_amdgcn_mfma_f32_16x16x32_bf16(pa, vh, O[nf], 0, 0, 0);
        O[nf] = __builtin_amdgcn_mfma_f32_16x16x32_bf16(pa, vl, O[nf], 0, 0, 0);
        O[nf] = __builtin_amdgcn_mfma_f32_16x16x32_bf16(pb, vh, O[nf], 0, 0, 0);
      }
    }

    // ---- res[b,q,s][hh*64+d]: row qo = w*16 + l4*4 + j, col d = nf*16+l15
#pragma unroll
    for (int nf = 0; nf < 4; ++nf)
#pragma unroll
      for (int j = 0; j < 4; ++j) {
        const int qo = w * 16 + l4 * 4 + j;
        const size_t idx =
            ((size_t)((b * 64 + qo) * 64 + s0 + si)) * HDIM + hh * 64 + nf * 16 + l15;
        const float v = O[nf][j];
        const bf16_t hb = (bf16_t)v;
        resh[idx] = hb;
        resl[idx] = (bf16_t)(v - (float)hb);
      }
    __syncthreads();  // new K visible; VT/P stable until here
  }
}

// ---------------- launch ----------------
extern "C" void kernel_launch(void* const* d_in, const int* in_sizes, int n_in,
                              void* d_out, int out_size, void* d_ws, size_t ws_size,
                              hipStream_t stream) {
  const float* ini_q = (const float*)d_in[0];
  const float* ini_k = (const float*)d_in[1];
  const float* mask = (const float*)d_in[2];
  const float* Wq = (const float*)d_in[3];
  const float* Wkv = (const float*)d_in[4];
  const float* Wo = (const float*)d_in[5];
  const float* bo = (const float*)d_in[6];
  float* out = (float*)d_out;

  const size_t SQ = 512ull * HDIM;
  const size_t SK = 32768ull * HDIM;
  const size_t SW = 768ull * HDIM;

  char* p = (char*)d_ws;
  auto carve = [&](size_t bytes) {
    char* r = p;
    p += (bytes + 255) & ~(size_t)255;
    return r;
  };
  bf16_t* wq_h = (bf16_t*)carve(SW * 2);
  bf16_t* wq_l = (bf16_t*)carve(SW * 2);
  bf16_t* wkv_h = (bf16_t*)carve(SW * 2);
  bf16_t* wkv_l = (bf16_t*)carve(SW * 2);
  bf16_t* wo_h = (bf16_t*)carve(SW * 2);
  bf16_t* wo_l = (bf16_t*)carve(SW * 2);
  bf16_t* q_h = (bf16_t*)carve(SQ * 2);
  bf16_t* q_l = (bf16_t*)carve(SQ * 2);
  bf16_t* kvN_h = (bf16_t*)carve(SK * 2);
  bf16_t* kvN_l = (bf16_t*)carve(SK * 2);
  bf16_t* res_h = (bf16_t*)carve(SK * 2);
  bf16_t* res_l = (bf16_t*)carve(SK * 2);
  if ((size_t)(p - (char*)d_ws) > ws_size) return;  // ws too small: fail visibly

  splitT3_kernel<<<dim3(12, 12, 3), 256, 0, stream>>>(
      Wq, Wkv, Wo, wq_h, wq_l, wkv_h, wkv_l, wo_h, wo_l);

  // q = ini_q @ Wq
  gemm_kernel<0, true><<<dim3(24), 256, 0, stream>>>(
      ini_q, nullptr, nullptr, wq_h, wq_l, q_h, q_l, nullptr, nullptr,
      nullptr, nullptr);
  // kv = ini_k @ Wkv -> kvN only
  gemm_kernel<2, true><<<dim3(1536), 256, 0, stream>>>(
      ini_k, nullptr, nullptr, wkv_h, wkv_l, nullptr, nullptr, kvN_h, kvN_l,
      nullptr, nullptr);
  // attention
  attn_kernel<<<dim3(8, 12, 8), 256, 0, stream>>>(
      q_h, q_l, kvN_h, kvN_l, mask, res_h, res_l);
  // out = res @ Wo + bo
  gemm_kernel<1, false><<<dim3(1536), 256, 0, stream>>>(
      nullptr, res_h, res_l, wo_h, wo_l, nullptr, nullptr, nullptr, nullptr,
      out, bo);
}